// Round 5
// baseline (250.357 us; speedup 1.0000x reference)
//
#include <hip/hip_runtime.h>

typedef unsigned short ushort_t;
typedef unsigned int uint_t;
typedef __attribute__((ext_vector_type(8))) short short8;   // 8 x bf16 (4 VGPRs)
typedef __attribute__((ext_vector_type(4))) float f32x4;

#define B_   128
#define S_   1024
#define H_   256
#define T_   10
#define NEG_INF_ -1e8f

static __device__ __forceinline__ ushort_t f2bf(float x) {
    unsigned int u = __float_as_uint(x);
    unsigned int r = u + 0x7FFFu + ((u >> 16) & 1u);   // RNE
    return (ushort_t)(r >> 16);
}
static __device__ __forceinline__ float bf2f(ushort_t u) {
    return __uint_as_float(((unsigned int)u) << 16);
}
static __device__ __forceinline__ float sigf(float x) {
    return 1.0f / (1.0f + __expf(-x));
}
static __device__ __forceinline__ float tanh_acc(float x) {
    return 2.0f / (1.0f + __expf(-2.0f * x)) - 1.0f;
}
// clamped odd poly tanh: 5 VALU, |err|<~0.025 (threshold 2e6)
static __device__ __forceinline__ float tanh_fast(float x) {
    float u = x * x;
    float p = fmaf(0.019063f, u, -0.18852f);
    p = fmaf(p, u, 0.93106f);
    float r = x * p;
    return __builtin_amdgcn_fmed3f(r, -1.0f, 1.0f);
}
static __device__ __forceinline__ short8 pack_bf8(float4 a, float4 b) {
    short8 r;
    r[0] = (short)f2bf(a.x); r[1] = (short)f2bf(a.y);
    r[2] = (short)f2bf(a.z); r[3] = (short)f2bf(a.w);
    r[4] = (short)f2bf(b.x); r[5] = (short)f2bf(b.y);
    r[6] = (short)f2bf(b.z); r[7] = (short)f2bf(b.w);
    return r;
}

// ---------------------------------------------------------------------------
// prep_conv: W_hh/Wq/Wd -> bf16 row-major, mask output.
// grid = 1792*256 = 458752 exactly.
// ---------------------------------------------------------------------------
__global__ void prep_conv(const float* __restrict__ W_hh, const float* __restrict__ Wq,
                          const float* __restrict__ Wd, const int* __restrict__ slen,
                          ushort_t* __restrict__ Whh_bf, ushort_t* __restrict__ Wq_bf,
                          ushort_t* __restrict__ Wd_bf, float* __restrict__ out_mask) {
    int i = blockIdx.x * 256 + threadIdx.x;
    if (i < 196608) { Whh_bf[i] = f2bf(W_hh[i]); return; }
    i -= 196608;
    if (i < 65536) { Wq_bf[i] = f2bf(Wq[i]); return; }
    i -= 65536;
    if (i < 65536) { Wd_bf[i] = f2bf(Wd[i]); return; }
    i -= 65536;
    int b = i >> 10, s = i & 1023;
    out_mask[i] = (s >= slen[b]) ? 1.0f : 0.0f;
}

// ---------------------------------------------------------------------------
// prep_gi: gi_T[t][col(768)][b] = x(t,b) @ W_ih^T + b_ih  (transposed output
// so gru_all's pointwise loads are f32x4 over batch).
// block = 8 rows of (t,b) x all 768 cols; grid = 160.
// ---------------------------------------------------------------------------
__global__ void prep_gi(const float* __restrict__ s0, const float* __restrict__ doc,
                        const int* __restrict__ tgt, const float* __restrict__ W_ih,
                        const float* __restrict__ b_ih, float* __restrict__ gi_T) {
    __shared__ float xs[8][256];
    const int r0 = blockIdx.x * 8;
    const int tid = threadIdx.x;
    for (int i = tid; i < 512; i += 256) {
        int row = i >> 6, c4 = i & 63;
        int r = r0 + row;              // r = t*128 + b
        int t = r >> 7, b = r & 127;
        const float* src;
        if (t == 0) src = s0 + (size_t)b * H_;
        else {
            int idx = tgt[b * T_ + t - 1];
            if (idx < 0) idx = 0;
            src = doc + ((size_t)b * S_ + idx) * H_;
        }
        *((float4*)&xs[row][c4 * 4]) = ((const float4*)src)[c4];
    }
    __syncthreads();
    const int j = tid;
    float acc[8][3];
#pragma unroll
    for (int r = 0; r < 8; ++r) { acc[r][0] = 0.f; acc[r][1] = 0.f; acc[r][2] = 0.f; }
    const float4* w0p = (const float4*)(W_ih + (size_t)j * H_);
    const float4* w1p = (const float4*)(W_ih + (size_t)(j + 256) * H_);
    const float4* w2p = (const float4*)(W_ih + (size_t)(j + 512) * H_);
    for (int c4 = 0; c4 < 64; ++c4) {
        float4 w0 = w0p[c4], w1 = w1p[c4], w2 = w2p[c4];
#pragma unroll
        for (int r = 0; r < 8; ++r) {
            float4 x4 = *((const float4*)&xs[r][c4 * 4]);
            acc[r][0] = fmaf(w0.x, x4.x, acc[r][0]); acc[r][0] = fmaf(w0.y, x4.y, acc[r][0]);
            acc[r][0] = fmaf(w0.z, x4.z, acc[r][0]); acc[r][0] = fmaf(w0.w, x4.w, acc[r][0]);
            acc[r][1] = fmaf(w1.x, x4.x, acc[r][1]); acc[r][1] = fmaf(w1.y, x4.y, acc[r][1]);
            acc[r][1] = fmaf(w1.z, x4.z, acc[r][1]); acc[r][1] = fmaf(w1.w, x4.w, acc[r][1]);
            acc[r][2] = fmaf(w2.x, x4.x, acc[r][2]); acc[r][2] = fmaf(w2.y, x4.y, acc[r][2]);
            acc[r][2] = fmaf(w2.z, x4.z, acc[r][2]); acc[r][2] = fmaf(w2.w, x4.w, acc[r][2]);
        }
    }
#pragma unroll
    for (int r = 0; r < 8; ++r) {
        int row = r0 + r;                 // t*128 + b
        int t = row >> 7, b = row & 127;
#pragma unroll
        for (int g = 0; g < 3; ++g)
            gi_T[((size_t)t * 768 + g * 256 + j) * B_ + b] = acc[r][g] + b_ih[g * 256 + j];
    }
}

// ---------------------------------------------------------------------------
// gru_all: 8 blocks x 512 threads (block = 16 batches). Per step: one
// [16 x 1024 x 256] bf16 MFMA GEMM (gates 768 + q 256). Wave w owns output
// cols {r,z,n,q} x [32w,32w+32) -> pointwise gate math is lane-local.
// h: LDS bf16 [16][256], XOR-swizzled; A-frags shared by all waves.
// Weights: bf16 row-major, streamed L2->VGPR fragments (disjoint per wave).
// ---------------------------------------------------------------------------
__global__ __launch_bounds__(512, 2) void gru_all(
        const float* __restrict__ h0, const ushort_t* __restrict__ Whh_bf,
        const ushort_t* __restrict__ Wq_bf, const float* __restrict__ b_hh,
        const float* __restrict__ bq, const float* __restrict__ gi_T,
        float* __restrict__ targets) {
    __shared__ char hbf[16 * 512];        // h [16][256] bf16, byte ^= ((b&7)<<4)
    const int tid = threadIdx.x;
    const int wv = tid >> 6, lane = tid & 63;
    const int r16 = lane & 15, g = lane >> 4;
    const int b0 = blockIdx.x * 16;

    // init h0 -> LDS bf16 (512 threads x 8 elems = 16*256)
    {
        int b = tid >> 5, k8 = (tid & 31) * 8;
        const float* src = h0 + (size_t)(b0 + b) * H_ + k8;
        float4 v0 = *((const float4*)src);
        float4 v1 = *((const float4*)(src + 4));
        short8 p = pack_bf8(v0, v1);
        int byte = (b * 512 + k8 * 2) ^ ((b & 7) << 4);
        *((short8*)&hbf[byte]) = p;
    }

    const int c0 = 32 * wv + r16;         // u=0 col within gate plane
    const int c1 = c0 + 16;               // u=1 col
    const float bhr0 = b_hh[c0],       bhr1 = b_hh[c1];
    const float bhz0 = b_hh[256 + c0], bhz1 = b_hh[256 + c1];
    const float bhn0 = b_hh[512 + c0], bhn1 = b_hh[512 + c1];
    const float bq0 = bq[c0], bq1 = bq[c1];

    // weight fragment bases: tile i<6 -> W_hh row (i>>1)*256 + 32w + 16(i&1) + r16
    const ushort_t* wg_base[6];
#pragma unroll
    for (int i = 0; i < 6; ++i)
        wg_base[i] = Whh_bf + ((size_t)((i >> 1) * 256 + 32 * wv + 16 * (i & 1) + r16)) * H_ + g * 8;
    const ushort_t* wq_base[2];
#pragma unroll
    for (int i = 0; i < 2; ++i)
        wq_base[i] = Wq_bf + ((size_t)(32 * wv + 16 * i + r16)) * H_ + g * 8;

    __syncthreads();

    // A-fragments of h(t-1): lane holds h[b=r16][k = ks*32 + g*8 .. +8]
    short8 af[8];
#pragma unroll
    for (int ks = 0; ks < 8; ++ks) {
        int byte = (r16 * 512 + ks * 64 + g * 16) ^ ((r16 & 7) << 4);
        af[ks] = *((const short8*)&hbf[byte]);
    }

    for (int t = 0; t < T_; ++t) {
        // --- gates GEMM: 6 N-tiles (r0,r1,z0,z1,n0,n1), 48 MFMA ---
        f32x4 acc[6];
#pragma unroll
        for (int i = 0; i < 6; ++i) acc[i] = (f32x4){0.f, 0.f, 0.f, 0.f};
#pragma unroll
        for (int i = 0; i < 6; ++i) {
            short8 wf[8];
#pragma unroll
            for (int ks = 0; ks < 8; ++ks) wf[ks] = *((const short8*)(wg_base[i] + ks * 32));
#pragma unroll
            for (int ks = 0; ks < 8; ++ks)
                acc[i] = __builtin_amdgcn_mfma_f32_16x16x32_bf16(af[ks], wf[ks], acc[i], 0, 0, 0);
        }

        // --- gi loads (f32x4 over batch) ---
        const float* gt = gi_T + (size_t)t * 768 * B_ + b0 + g * 4;
        f32x4 gir0 = *((const f32x4*)(gt + (size_t)(c0) * B_));
        f32x4 gir1 = *((const f32x4*)(gt + (size_t)(c1) * B_));
        f32x4 giz0 = *((const f32x4*)(gt + (size_t)(256 + c0) * B_));
        f32x4 giz1 = *((const f32x4*)(gt + (size_t)(256 + c1) * B_));
        f32x4 gin0 = *((const f32x4*)(gt + (size_t)(512 + c0) * B_));
        f32x4 gin1 = *((const f32x4*)(gt + (size_t)(512 + c1) * B_));

        // --- pointwise: lane owns (b = g*4+rr, cols c0,c1) ---
        float hnew0[4], hnew1[4];
#pragma unroll
        for (int rr = 0; rr < 4; ++rr) {
            int bb = g * 4 + rr;
            int byA = (bb * 512 + c0 * 2) ^ ((bb & 7) << 4);
            int byB = (bb * 512 + c1 * 2) ^ ((bb & 7) << 4);
            float ho0 = bf2f(*((const ushort_t*)&hbf[byA]));
            float ho1 = bf2f(*((const ushort_t*)&hbf[byB]));
            float r0v = sigf(gir0[rr] + acc[0][rr] + bhr0);
            float r1v = sigf(gir1[rr] + acc[1][rr] + bhr1);
            float z0v = sigf(giz0[rr] + acc[2][rr] + bhz0);
            float z1v = sigf(giz1[rr] + acc[3][rr] + bhz1);
            float n0v = tanh_acc(fmaf(r0v, acc[4][rr] + bhn0, gin0[rr]));
            float n1v = tanh_acc(fmaf(r1v, acc[5][rr] + bhn1, gin1[rr]));
            hnew0[rr] = n0v + z0v * (ho0 - n0v);
            hnew1[rr] = n1v + z1v * (ho1 - n1v);
        }
        __syncthreads();   // all reads of h(t-1) complete
#pragma unroll
        for (int rr = 0; rr < 4; ++rr) {
            int bb = g * 4 + rr;
            int byA = (bb * 512 + c0 * 2) ^ ((bb & 7) << 4);
            int byB = (bb * 512 + c1 * 2) ^ ((bb & 7) << 4);
            *((ushort_t*)&hbf[byA]) = f2bf(hnew0[rr]);
            *((ushort_t*)&hbf[byB]) = f2bf(hnew1[rr]);
        }
        __syncthreads();   // h(t) visible

        // --- reload A-frags with h(t) (also used next iteration) ---
#pragma unroll
        for (int ks = 0; ks < 8; ++ks) {
            int byte = (r16 * 512 + ks * 64 + g * 16) ^ ((r16 & 7) << 4);
            af[ks] = *((const short8*)&hbf[byte]);
        }

        // --- q GEMM: 2 N-tiles, 16 MFMA ---
        f32x4 accq0 = (f32x4){0.f, 0.f, 0.f, 0.f};
        f32x4 accq1 = (f32x4){0.f, 0.f, 0.f, 0.f};
        {
            short8 wf[8];
#pragma unroll
            for (int ks = 0; ks < 8; ++ks) wf[ks] = *((const short8*)(wq_base[0] + ks * 32));
#pragma unroll
            for (int ks = 0; ks < 8; ++ks)
                accq0 = __builtin_amdgcn_mfma_f32_16x16x32_bf16(af[ks], wf[ks], accq0, 0, 0, 0);
#pragma unroll
            for (int ks = 0; ks < 8; ++ks) wf[ks] = *((const short8*)(wq_base[1] + ks * 32));
#pragma unroll
            for (int ks = 0; ks < 8; ++ks)
                accq1 = __builtin_amdgcn_mfma_f32_16x16x32_bf16(af[ks], wf[ks], accq1, 0, 0, 0);
        }
#pragma unroll
        for (int rr = 0; rr < 4; ++rr) {
            int bb = b0 + g * 4 + rr;
            targets[((size_t)t * B_ + bb) * H_ + c0] = accq0[rr] + bq0;
            targets[((size_t)t * B_ + bb) * H_ + c1] = accq1[rr] + bq1;
        }
    }
}

// ---------------------------------------------------------------------------
// energy: block (b, s-tile of 128 = TWO 64-row MFMA tiles). Wd fragments and
// tg/ws LDS reads shared by both tiles. D layout: col(lane&15)=s, row=k.
// (unchanged from R4)
// ---------------------------------------------------------------------------
__global__ __launch_bounds__(256, 3) void energy_kernel(
        const float* __restrict__ doc, const ushort_t* __restrict__ Wd_bf,
        const float* __restrict__ targets, const float* __restrict__ bd,
        const float* __restrict__ Ws, const float* __restrict__ bs,
        const int* __restrict__ slenp, float* __restrict__ out) {
    __shared__ float tg[T_][256];
    __shared__ float ws_l[256], bd_l[256];
    const int bid = blockIdx.x;
    const int b = bid >> 3, st = bid & 7;
    const int tid = threadIdx.x;

    for (int i = tid; i < 640; i += 256) {
        int t = i >> 6, k4 = i & 63;
        ((float4*)&tg[t][0])[k4] = *((const float4*)&targets[((size_t)t * B_ + b) * H_ + k4 * 4]);
    }
    if (tid < 64) ((float4*)ws_l)[tid] = ((const float4*)Ws)[tid];
    else if (tid < 128) ((float4*)bd_l)[tid - 64] = ((const float4*)bd)[tid - 64];

    const int lane = tid & 63, w = tid >> 6;
    const int r16 = lane & 15, g = lane >> 4;

    const int s0_loc = st * 128 + w * 16 + r16;
    const float* drow0 = doc + ((size_t)b * S_ + s0_loc) * H_ + g * 8;
    const float* drow1 = drow0 + (size_t)64 * H_;
    short8 bdoc0[8], bdoc1[8];
#pragma unroll
    for (int ks = 0; ks < 8; ++ks) {
        float4 v0 = *((const float4*)(drow0 + ks * 32));
        float4 v1 = *((const float4*)(drow0 + ks * 32 + 4));
        bdoc0[ks] = pack_bf8(v0, v1);
        float4 u0 = *((const float4*)(drow1 + ks * 32));
        float4 u1 = *((const float4*)(drow1 + ks * 32 + 4));
        bdoc1[ks] = pack_bf8(u0, u1);
    }
    __syncthreads();

    float e0[T_], e1[T_];
#pragma unroll
    for (int t = 0; t < T_; ++t) { e0[t] = 0.f; e1[t] = 0.f; }

    const ushort_t* wbase = Wd_bf + (size_t)r16 * H_ + g * 8;
    const int kq = g * 4;

#pragma unroll 2
    for (int nt = 0; nt < 16; ++nt) {
        const int k0 = nt * 16 + kq;
        const ushort_t* wrow = wbase + (size_t)(nt * 16) * H_;
        short8 awd[8];
#pragma unroll
        for (int ks = 0; ks < 8; ++ks) awd[ks] = *((const short8*)(wrow + ks * 32));
        f32x4 bd4 = *((const f32x4*)&bd_l[k0]);
        f32x4 a00 = bd4;
        f32x4 a01 = {0.f, 0.f, 0.f, 0.f};
        f32x4 a10 = bd4;
        f32x4 a11 = {0.f, 0.f, 0.f, 0.f};
#pragma unroll
        for (int ks = 0; ks < 4; ++ks) {
            a00 = __builtin_amdgcn_mfma_f32_16x16x32_bf16(awd[ks],     bdoc0[ks],     a00, 0, 0, 0);
            a01 = __builtin_amdgcn_mfma_f32_16x16x32_bf16(awd[ks + 4], bdoc0[ks + 4], a01, 0, 0, 0);
            a10 = __builtin_amdgcn_mfma_f32_16x16x32_bf16(awd[ks],     bdoc1[ks],     a10, 0, 0, 0);
            a11 = __builtin_amdgcn_mfma_f32_16x16x32_bf16(awd[ks + 4], bdoc1[ks + 4], a11, 0, 0, 0);
        }
        f32x4 pA = a00 + a01;
        f32x4 pB = a10 + a11;
        f32x4 ws4 = *((const f32x4*)&ws_l[k0]);
#pragma unroll
        for (int t = 0; t < T_; ++t) {
            f32x4 tg4 = *((const f32x4*)&tg[t][k0]);
#pragma unroll
            for (int rr = 0; rr < 4; ++rr) {
                e0[t] = fmaf(tanh_fast(pA[rr] + tg4[rr]), ws4[rr], e0[t]);
                e1[t] = fmaf(tanh_fast(pB[rr] + tg4[rr]), ws4[rr], e1[t]);
            }
        }
    }

#pragma unroll
    for (int t = 0; t < T_; ++t) {
        e0[t] += __shfl_xor(e0[t], 16);
        e0[t] += __shfl_xor(e0[t], 32);
        e1[t] += __shfl_xor(e1[t], 16);
        e1[t] += __shfl_xor(e1[t], 32);
    }

    const int slen = slenp[b];
    const float bs0 = bs[0];
    const bool pad0 = (s0_loc >= slen);
    const bool pad1 = (s0_loc + 64 >= slen);
    float* obase = out + (size_t)b * S_ + s0_loc;
#pragma unroll
    for (int tt = g; tt < T_; tt += 4) {
        obase[(size_t)tt * B_ * S_]      = pad0 ? NEG_INF_ : (e0[tt] + bs0);
        obase[(size_t)tt * B_ * S_ + 64] = pad1 ? NEG_INF_ : (e1[tt] + bs0);
    }
}

// ---------------------------------------------------------------------------
extern "C" void kernel_launch(void* const* d_in, const int* in_sizes, int n_in,
                              void* d_out, int out_size, void* d_ws, size_t ws_size,
                              hipStream_t stream) {
    (void)in_sizes; (void)n_in; (void)out_size; (void)ws_size;
    const float* s0   = (const float*)d_in[0];
    const float* h0   = (const float*)d_in[1];
    const float* doc  = (const float*)d_in[2];
    const float* W_ih = (const float*)d_in[3];
    const float* W_hh = (const float*)d_in[4];
    const float* b_ih = (const float*)d_in[5];
    const float* b_hh = (const float*)d_in[6];
    const float* Wq   = (const float*)d_in[7];
    const float* bq   = (const float*)d_in[8];
    const float* Wd   = (const float*)d_in[9];
    const float* bd   = (const float*)d_in[10];
    const float* Ws   = (const float*)d_in[11];
    const float* bs   = (const float*)d_in[12];
    const int*   tgt  = (const int*)d_in[13];
    const int*   slen = (const int*)d_in[14];

    float* out_score = (float*)d_out;                       // [10][128][1024]
    float* out_mask  = out_score + T_ * B_ * S_;            // [128][1024]

    char* ws = (char*)d_ws;
    ushort_t* Whh_bf  = (ushort_t*)(ws + 0);                //  393216 B
    ushort_t* Wq_bf   = (ushort_t*)(ws + 393216);           //  131072 B
    ushort_t* Wd_bf   = (ushort_t*)(ws + 524288);           //  131072 B
    float*    gi_T    = (float*)(ws + 655360);              // 3932160 B
    float*    targets = (float*)(ws + 4587520);             // 1310720 B (end 5898240)

    prep_conv<<<1792, 256, 0, stream>>>(W_hh, Wq, Wd, slen, Whh_bf, Wq_bf, Wd_bf, out_mask);
    prep_gi<<<160, 256, 0, stream>>>(s0, doc, tgt, W_ih, b_ih, gi_T);
    gru_all<<<8, 512, 0, stream>>>(h0, Whh_bf, Wq_bf, b_hh, bq, gi_T, targets);
    energy_kernel<<<1024, 256, 0, stream>>>(doc, Wd_bf, targets, bd, Ws, bs, slen, out_score);
}